// Round 1
// baseline (352.268 us; speedup 1.0000x reference)
//
#include <hip/hip_runtime.h>

typedef __bf16 bf16;
typedef __bf16 bf16x4 __attribute__((ext_vector_type(4)));
typedef __bf16 bf16x8 __attribute__((ext_vector_type(8)));
typedef float  f32x4  __attribute__((ext_vector_type(4)));

#define OC_N   4096
#define IC_K   4096
#define TOKENS 4096

// ---------------------------------------------------------------------------
// Kernel 1: xnor quant of weight rows -> bf16 into workspace.
// One block per output-channel row. 256 threads x 16 floats = 4096, held in
// registers across both reduction passes (mean, mean|.|) and the write.
// ---------------------------------------------------------------------------
__global__ __launch_bounds__(256) void quant_weight_kernel(
    const float* __restrict__ w, bf16* __restrict__ wb)
{
    __shared__ float red[8];
    const int row = blockIdx.x;
    const int t = threadIdx.x;
    const float4* wr = (const float4*)(w + (size_t)row * IC_K);

    float4 v[4];
    float s = 0.f;
#pragma unroll
    for (int i = 0; i < 4; i++) {
        v[i] = wr[i * 256 + t];
        s += v[i].x + v[i].y + v[i].z + v[i].w;
    }
    for (int o = 32; o > 0; o >>= 1) s += __shfl_down(s, o, 64);
    const int lane = t & 63, wv = t >> 6;
    if (lane == 0) red[wv] = s;
    __syncthreads();
    const float mean = (red[0] + red[1] + red[2] + red[3]) * (1.f / IC_K);

    float sa = 0.f;
#pragma unroll
    for (int i = 0; i < 4; i++) {
        sa += fabsf(v[i].x - mean) + fabsf(v[i].y - mean) +
              fabsf(v[i].z - mean) + fabsf(v[i].w - mean);
    }
    for (int o = 32; o > 0; o >>= 1) sa += __shfl_down(sa, o, 64);
    if (lane == 0) red[4 + wv] = sa;
    __syncthreads();
    const float scale = (red[4] + red[5] + red[6] + red[7]) * (1.f / IC_K);

    bf16* out = wb + (size_t)row * IC_K;
#pragma unroll
    for (int i = 0; i < 4; i++) {
        float c[4] = { v[i].x - mean, v[i].y - mean, v[i].z - mean, v[i].w - mean };
        bf16x4 q;
#pragma unroll
        for (int j = 0; j < 4; j++)
            q[j] = (bf16)(c[j] > 0.f ? scale : (c[j] < 0.f ? -scale : 0.f));
        *(bf16x4*)(out + (size_t)(i * 256 + t) * 4) = q;
    }
}

// ---------------------------------------------------------------------------
// Kernel 2: scatter full-precision outlier columns over the quantized weight.
// ---------------------------------------------------------------------------
__global__ void scatter_outliers_kernel(
    const float* __restrict__ ow, const int* __restrict__ idx,
    bf16* __restrict__ wb, int n_out)
{
    const int o = blockIdx.x;
    for (int c = threadIdx.x; c < n_out; c += blockDim.x)
        wb[(size_t)o * IC_K + idx[c]] = (bf16)ow[(size_t)o * n_out + c];
}

// ---------------------------------------------------------------------------
// Kernel 3: x fp32 -> bf16 (8 elems/thread: 2x float4 in, one 16B store out)
// ---------------------------------------------------------------------------
__global__ __launch_bounds__(256) void convert_x_kernel(
    const float* __restrict__ x, bf16* __restrict__ xb)
{
    const size_t i = ((size_t)blockIdx.x * 256 + threadIdx.x) * 8;
    float4 a = *(const float4*)(x + i);
    float4 b = *(const float4*)(x + i + 4);
    bf16x8 o;
    o[0] = (bf16)a.x; o[1] = (bf16)a.y; o[2] = (bf16)a.z; o[3] = (bf16)a.w;
    o[4] = (bf16)b.x; o[5] = (bf16)b.y; o[6] = (bf16)b.z; o[7] = (bf16)b.w;
    *(bf16x8*)(xb + i) = o;
}

// ---------------------------------------------------------------------------
// Kernel 4: bf16 GEMM, C = A @ B^T + bias.  A[T][K], B[N][K] both K-major.
// m97 structure: 128x128 tile, BK=32, 4 waves each 64x64 via 4x4
// mfma_f32_16x16x32_bf16, global_load_lds width-16 staging.
// ---------------------------------------------------------------------------
__device__ __forceinline__ void gload_lds16(const bf16* g, bf16* l)
{
    __builtin_amdgcn_global_load_lds(
        (const __attribute__((address_space(1))) void*)g,
        (__attribute__((address_space(3))) void*)l, 16, 0, 0);
}

__global__ __launch_bounds__(256) void gemm_bt_kernel(
    const bf16* __restrict__ A, const bf16* __restrict__ B,
    const float* __restrict__ bias, float* __restrict__ C)
{
    constexpr int K = IC_K, N = OC_N, BK = 32, TM = 128, TN = 128;
    __shared__ __align__(16) bf16 As[TM * BK];
    __shared__ __align__(16) bf16 Bs[TN * BK];

    const int bm = blockIdx.y, bn = blockIdx.x;
    const int tid = threadIdx.x, lane = tid & 63, wave = tid >> 6;
    const int wm = wave >> 1, wn = wave & 1;

    // Staging: per wave two 1KB chunks per tile. Chunk = 16 rows x 32 bf16.
    // Lane l -> row (l>>2) within chunk, k-offset (l&3)*8 (16B per lane).
    const bf16* ga = A + (size_t)(bm * TM + wave * 32 + (lane >> 2)) * K + (lane & 3) * 8;
    const bf16* gb = B + (size_t)(bn * TN + wave * 32 + (lane >> 2)) * K + (lane & 3) * 8;
    bf16* lA = &As[wave * 32 * BK];
    bf16* lB = &Bs[wave * 32 * BK];

    f32x4 acc[4][4] = {};

    for (int k0 = 0; k0 < K; k0 += BK) {
        gload_lds16(ga + k0,            lA);
        gload_lds16(ga + k0 + 16 * K,   lA + 16 * BK);
        gload_lds16(gb + k0,            lB);
        gload_lds16(gb + k0 + 16 * K,   lB + 16 * BK);
        __syncthreads();

        bf16x8 af[4], bfr[4];
#pragma unroll
        for (int i = 0; i < 4; i++)
            af[i] = *(const bf16x8*)&As[(wm * 64 + i * 16 + (lane & 15)) * BK + (lane >> 4) * 8];
#pragma unroll
        for (int i = 0; i < 4; i++)
            bfr[i] = *(const bf16x8*)&Bs[(wn * 64 + i * 16 + (lane & 15)) * BK + (lane >> 4) * 8];
#pragma unroll
        for (int mi = 0; mi < 4; mi++)
#pragma unroll
            for (int ni = 0; ni < 4; ni++)
                acc[mi][ni] = __builtin_amdgcn_mfma_f32_16x16x32_bf16(
                    af[mi], bfr[ni], acc[mi][ni], 0, 0, 0);
        __syncthreads();
    }

    // C/D layout: col = lane&15, row = (lane>>4)*4 + reg  [m89/m91 verified]
    const int col0 = bn * TN + wn * 64 + (lane & 15);
    const int row0 = bm * TM + wm * 64 + (lane >> 4) * 4;
#pragma unroll
    for (int ni = 0; ni < 4; ni++) {
        const float bv = bias[col0 + ni * 16];
#pragma unroll
        for (int mi = 0; mi < 4; mi++) {
#pragma unroll
            for (int r = 0; r < 4; r++) {
                C[(size_t)(row0 + mi * 16 + r) * N + col0 + ni * 16] =
                    acc[mi][ni][r] + bv;
            }
        }
    }
}

// ---------------------------------------------------------------------------
extern "C" void kernel_launch(void* const* d_in, const int* in_sizes, int n_in,
                              void* d_out, int out_size, void* d_ws, size_t ws_size,
                              hipStream_t stream)
{
    const float* x    = (const float*)d_in[0];
    const float* w    = (const float*)d_in[1];
    const float* bias = (const float*)d_in[2];
    const float* ow   = (const float*)d_in[3];
    const int*   idx  = (const int*)d_in[4];
    const int    n_out = in_sizes[4];
    float* out = (float*)d_out;

    bf16* xb = (bf16*)d_ws;                         // 32 MB
    bf16* wb = xb + (size_t)TOKENS * IC_K;          // 32 MB

    hipLaunchKernelGGL(quant_weight_kernel, dim3(OC_N), dim3(256), 0, stream, w, wb);
    hipLaunchKernelGGL(scatter_outliers_kernel, dim3(OC_N), dim3(256), 0, stream,
                       ow, idx, wb, n_out);
    hipLaunchKernelGGL(convert_x_kernel, dim3((TOKENS * (size_t)IC_K) / 2048),
                       dim3(256), 0, stream, x, xb);
    hipLaunchKernelGGL(gemm_bt_kernel, dim3(OC_N / 128, TOKENS / 128), dim3(256),
                       0, stream, xb, wb, bias, out);
}

// Round 3
// 307.361 us; speedup vs baseline: 1.1461x; 1.1461x over previous
//
#include <hip/hip_runtime.h>

typedef __bf16 bf16;
typedef __bf16 bf16x4 __attribute__((ext_vector_type(4)));
typedef __bf16 bf16x8 __attribute__((ext_vector_type(8)));
typedef float  f32x4  __attribute__((ext_vector_type(4)));

#define OC_N   4096
#define IC_K   4096
#define TOKENS 4096

// ---------------------------------------------------------------------------
// Fused prep: one block per row r (TOKENS == OC_N == 4096).
//   phase 1: quantize weight row r -> wb (sign(w-mean)*meanabs, bf16)
//   phase 2: scatter full-precision outlier columns over wb row r
//   phase 3: convert x row r fp32 -> bf16
// ---------------------------------------------------------------------------
__global__ __launch_bounds__(256) void prep_kernel_v2(
    const float* __restrict__ w, const float* __restrict__ x,
    const float* __restrict__ ow, const int* __restrict__ idx,
    bf16* __restrict__ wb, bf16* __restrict__ xb, int n_out)
{
    __shared__ float red[8];
    const int row = blockIdx.x;
    const int t = threadIdx.x;
    const int lane = t & 63, wv = t >> 6;

    // ---- phase 1: quantize weight row ----
    const float4* wr = (const float4*)(w + (size_t)row * IC_K);
    float4 v[4];
    float s = 0.f;
#pragma unroll
    for (int i = 0; i < 4; i++) {
        v[i] = wr[i * 256 + t];
        s += v[i].x + v[i].y + v[i].z + v[i].w;
    }
    for (int o = 32; o > 0; o >>= 1) s += __shfl_down(s, o, 64);
    if (lane == 0) red[wv] = s;
    __syncthreads();
    const float mean = (red[0] + red[1] + red[2] + red[3]) * (1.f / IC_K);

    float sa = 0.f;
#pragma unroll
    for (int i = 0; i < 4; i++) {
        sa += fabsf(v[i].x - mean) + fabsf(v[i].y - mean) +
              fabsf(v[i].z - mean) + fabsf(v[i].w - mean);
    }
    for (int o = 32; o > 0; o >>= 1) sa += __shfl_down(sa, o, 64);
    if (lane == 0) red[4 + wv] = sa;
    __syncthreads();
    const float scale = (red[4] + red[5] + red[6] + red[7]) * (1.f / IC_K);

    bf16* wrow = wb + (size_t)row * IC_K;
#pragma unroll
    for (int i = 0; i < 4; i++) {
        float c[4] = { v[i].x - mean, v[i].y - mean, v[i].z - mean, v[i].w - mean };
        bf16x4 q;
#pragma unroll
        for (int j = 0; j < 4; j++)
            q[j] = (bf16)(c[j] > 0.f ? scale : (c[j] < 0.f ? -scale : 0.f));
        *(bf16x4*)(wrow + (size_t)(i * 256 + t) * 4) = q;
    }

    // ---- phase 2: outlier scatter (ordered after quant stores, same block) ----
    __syncthreads();
    for (int c = t; c < n_out; c += 256)
        wrow[idx[c]] = (bf16)ow[(size_t)row * n_out + c];

    // ---- phase 3: x fp32 -> bf16, thread t owns 8 consecutive floats/half-row ----
    const float* xrow_in = x + (size_t)row * IC_K;
    bf16* xrow = xb + (size_t)row * IC_K;
#pragma unroll
    for (int i = 0; i < 2; i++) {
        const size_t off = (size_t)i * 2048 + (size_t)t * 8;
        float4 a = *(const float4*)(xrow_in + off);
        float4 b = *(const float4*)(xrow_in + off + 4);
        bf16x8 o8;
        o8[0] = (bf16)a.x; o8[1] = (bf16)a.y; o8[2] = (bf16)a.z; o8[3] = (bf16)a.w;
        o8[4] = (bf16)b.x; o8[5] = (bf16)b.y; o8[6] = (bf16)b.z; o8[7] = (bf16)b.w;
        *(bf16x8*)(xrow + off) = o8;
    }
}

// ---------------------------------------------------------------------------
// GEMM C = A @ B^T + bias.  128x128 tile, BK=64, XOR-swizzled LDS (rows are
// 128 B = full bank span; 16B quad q of row r lives at phys quad q^(r&7)).
// Swizzle is applied on the *global fetch side* so global_load_lds's fixed
// lane->LDS mapping produces the swizzled layout directly.
// ---------------------------------------------------------------------------
__device__ __forceinline__ void gload_lds16(const bf16* g, bf16* l)
{
    __builtin_amdgcn_global_load_lds(
        (const __attribute__((address_space(1))) void*)g,
        (__attribute__((address_space(3))) void*)l, 16, 0, 0);
}

__global__ __launch_bounds__(256) void gemm_bt_kernel(
    const bf16* __restrict__ A, const bf16* __restrict__ B,
    const float* __restrict__ bias, float* __restrict__ C)
{
    constexpr int K = IC_K, N = OC_N, BK = 64, TM = 128, TN = 128;
    __shared__ __align__(16) bf16 As[TM * BK];   // 16 KB
    __shared__ __align__(16) bf16 Bs[TN * BK];   // 16 KB

    const int bm = blockIdx.y, bn = blockIdx.x;
    const int tid = threadIdx.x, lane = tid & 63, wave = tid >> 6;
    const int wm = wave >> 1, wn = wave & 1;

    // Staging: each global_load_lds covers 8 rows x 128 B. Lane l -> row l>>3,
    // physical quad l&7, which holds logical k-quad (l&7)^(l>>3).
    const int srow = lane >> 3;
    const int soct = (lane & 7) ^ srow;          // logical k-quad to fetch
    const bf16* ga = A + (size_t)(bm * TM + wave * 32 + srow) * K + soct * 8;
    const bf16* gb = B + (size_t)(bn * TN + wave * 32 + srow) * K + soct * 8;
    bf16* lA = &As[wave * 32 * BK];
    bf16* lB = &Bs[wave * 32 * BK];

    // Fragment-read swizzle: row's low 3 bits = lane&7 (rows step by 16).
    const int rxor = lane & 7;

    f32x4 acc[4][4] = {};

    for (int k0 = 0; k0 < K; k0 += BK) {
#pragma unroll
        for (int i = 0; i < 4; i++) {
            gload_lds16(ga + k0 + (size_t)(i * 8) * K, lA + i * 8 * BK);
            gload_lds16(gb + k0 + (size_t)(i * 8) * K, lB + i * 8 * BK);
        }
        __syncthreads();

#pragma unroll
        for (int s = 0; s < 2; s++) {
            const int lq = s * 4 + (lane >> 4);      // logical k-quad
            const int pq = lq ^ rxor;                // physical quad
            bf16x8 af[4], bfr[4];
#pragma unroll
            for (int i = 0; i < 4; i++)
                af[i] = *(const bf16x8*)&As[(wm * 64 + i * 16 + (lane & 15)) * BK + pq * 8];
#pragma unroll
            for (int i = 0; i < 4; i++)
                bfr[i] = *(const bf16x8*)&Bs[(wn * 64 + i * 16 + (lane & 15)) * BK + pq * 8];
#pragma unroll
            for (int mi = 0; mi < 4; mi++)
#pragma unroll
                for (int ni = 0; ni < 4; ni++)
                    acc[mi][ni] = __builtin_amdgcn_mfma_f32_16x16x32_bf16(
                        af[mi], bfr[ni], acc[mi][ni], 0, 0, 0);
        }
        __syncthreads();
    }

    // C/D layout: col = lane&15, row = (lane>>4)*4 + reg  [m89/m91 verified]
    const int col0 = bn * TN + wn * 64 + (lane & 15);
    const int row0 = bm * TM + wm * 64 + (lane >> 4) * 4;
#pragma unroll
    for (int ni = 0; ni < 4; ni++) {
        const float bv = bias[col0 + ni * 16];
#pragma unroll
        for (int mi = 0; mi < 4; mi++) {
#pragma unroll
            for (int r = 0; r < 4; r++) {
                C[(size_t)(row0 + mi * 16 + r) * N + col0 + ni * 16] =
                    acc[mi][ni][r] + bv;
            }
        }
    }
}

// ---------------------------------------------------------------------------
extern "C" void kernel_launch(void* const* d_in, const int* in_sizes, int n_in,
                              void* d_out, int out_size, void* d_ws, size_t ws_size,
                              hipStream_t stream)
{
    const float* x    = (const float*)d_in[0];
    const float* w    = (const float*)d_in[1];
    const float* bias = (const float*)d_in[2];
    const float* ow   = (const float*)d_in[3];
    const int*   idx  = (const int*)d_in[4];
    const int    n_out = in_sizes[4];
    float* out = (float*)d_out;

    bf16* xb = (bf16*)d_ws;                         // 32 MB
    bf16* wb = xb + (size_t)TOKENS * IC_K;          // 32 MB

    hipLaunchKernelGGL(prep_kernel_v2, dim3(OC_N), dim3(256), 0, stream,
                       w, x, ow, idx, wb, xb, n_out);
    hipLaunchKernelGGL(gemm_bt_kernel, dim3(OC_N / 128, TOKENS / 128), dim3(256),
                       0, stream, xb, wb, bias, out);
}

// Round 4
// 258.275 us; speedup vs baseline: 1.3639x; 1.1900x over previous
//
#include <hip/hip_runtime.h>

typedef __bf16 bf16;
typedef __bf16 bf16x8 __attribute__((ext_vector_type(8)));
typedef float  f32x4  __attribute__((ext_vector_type(4)));
typedef int    i32x4  __attribute__((ext_vector_type(4)));
typedef signed char i8;

#define OC_N   4096
#define IC_K   4096
#define TOKENS 4096
#define KC     256   // outlier K padded to 8x32

// ---------------------------------------------------------------------------
// Fused prep, one block per row r (TOKENS == OC_N == 4096):
//   A: weight row -> mean, scale=mean|w-mean|, sign i8 {-1,0,1}; scale_arr
//   B: x row -> per-token absmax, sx=max/127, x i8; sx_arr
//   C: correction arrays (KC=256 padded):
//        xo[r][c]    = bf16( x[r][idx[c]] )
//        wcorr[r][c] = bf16( ow[r][c] - scale*sign(w[r][idx[c]]-mean) )
// ---------------------------------------------------------------------------
__global__ __launch_bounds__(256) void prep_kernel(
    const float* __restrict__ w, const float* __restrict__ x,
    const float* __restrict__ ow, const int* __restrict__ idx,
    i8* __restrict__ wsgn, i8* __restrict__ xq,
    bf16* __restrict__ xo, bf16* __restrict__ wcorr,
    float* __restrict__ scale_arr, float* __restrict__ sx_arr, int n_out)
{
    __shared__ float red[8];
    const int row = blockIdx.x;
    const int t = threadIdx.x;
    const int lane = t & 63, wv = t >> 6;

    // ---- phase A: weight row ----
    const float4* wr = (const float4*)(w + (size_t)row * IC_K);
    float4 v[4];
    float s = 0.f;
#pragma unroll
    for (int i = 0; i < 4; i++) {
        v[i] = wr[i * 256 + t];
        s += v[i].x + v[i].y + v[i].z + v[i].w;
    }
    for (int o = 32; o > 0; o >>= 1) s += __shfl_down(s, o, 64);
    if (lane == 0) red[wv] = s;
    __syncthreads();
    const float mean = (red[0] + red[1] + red[2] + red[3]) * (1.f / IC_K);

    float sa = 0.f;
#pragma unroll
    for (int i = 0; i < 4; i++) {
        sa += fabsf(v[i].x - mean) + fabsf(v[i].y - mean) +
              fabsf(v[i].z - mean) + fabsf(v[i].w - mean);
    }
    for (int o = 32; o > 0; o >>= 1) sa += __shfl_down(sa, o, 64);
    if (lane == 0) red[4 + wv] = sa;
    __syncthreads();
    const float scale = (red[4] + red[5] + red[6] + red[7]) * (1.f / IC_K);

    i8* srow = wsgn + (size_t)row * IC_K;
#pragma unroll
    for (int i = 0; i < 4; i++) {
        float c[4] = { v[i].x - mean, v[i].y - mean, v[i].z - mean, v[i].w - mean };
        char4 q;
        q.x = (i8)((c[0] > 0.f) - (c[0] < 0.f));
        q.y = (i8)((c[1] > 0.f) - (c[1] < 0.f));
        q.z = (i8)((c[2] > 0.f) - (c[2] < 0.f));
        q.w = (i8)((c[3] > 0.f) - (c[3] < 0.f));
        *(char4*)(srow + (size_t)(i * 256 + t) * 4) = q;
    }

    // ---- phase B: x row quantization ----
    const float4* xr = (const float4*)(x + (size_t)row * IC_K);
    float4 u[4];
    float mx = 0.f;
#pragma unroll
    for (int i = 0; i < 4; i++) {
        u[i] = xr[i * 256 + t];
        mx = fmaxf(mx, fmaxf(fmaxf(fabsf(u[i].x), fabsf(u[i].y)),
                             fmaxf(fabsf(u[i].z), fabsf(u[i].w))));
    }
    for (int o = 32; o > 0; o >>= 1) mx = fmaxf(mx, __shfl_down(mx, o, 64));
    if (lane == 0) red[wv] = mx;   // red[0..3] readers all done before sync#2
    __syncthreads();
    const float maxv = fmaxf(fmaxf(red[0], red[1]), fmaxf(red[2], red[3]));
    const float inv = maxv > 0.f ? 127.f / maxv : 0.f;
    const float sxv = maxv > 0.f ? maxv * (1.f / 127.f) : 1.f;

    i8* xrow = xq + (size_t)row * IC_K;
#pragma unroll
    for (int i = 0; i < 4; i++) {
        char4 q;
        q.x = (i8)(int)rintf(u[i].x * inv);
        q.y = (i8)(int)rintf(u[i].y * inv);
        q.z = (i8)(int)rintf(u[i].z * inv);
        q.w = (i8)(int)rintf(u[i].w * inv);
        *(char4*)(xrow + (size_t)(i * 256 + t) * 4) = q;
    }
    if (t == 0) { scale_arr[row] = scale; sx_arr[row] = sxv; }

    // ---- phase C: correction arrays (uses regs mean/scale only) ----
    if (t < n_out) {
        const int col = idx[t];
        xo[(size_t)row * KC + t] = (bf16)x[(size_t)row * IC_K + col];
        const float wc_ = w[(size_t)row * IC_K + col] - mean;
        const float sg = (wc_ > 0.f) ? 1.f : ((wc_ < 0.f) ? -1.f : 0.f);
        wcorr[(size_t)row * KC + t] = (bf16)(ow[(size_t)row * n_out + t] - scale * sg);
    } else if (t < KC) {
        xo[(size_t)row * KC + t] = (bf16)0.f;
        wcorr[(size_t)row * KC + t] = (bf16)0.f;
    }
}

// ---------------------------------------------------------------------------
// GEMM: C = sx[t]*scale[o]*(xq @ wsgn^T)_i32 + xo @ wcorr^T + bias
// i8 main loop: 128x128 tile, BK=128 bytes/row (same 128B-row XOR-swizzled
// LDS layout as the verified bf16 kernel), mfma_i32_16x16x64_i8.
// Correction loop: 4 bf16 BK=64 iterations reusing the same LDS buffers.
// ---------------------------------------------------------------------------
__device__ __forceinline__ void gload16(const void* g, void* l)
{
    __builtin_amdgcn_global_load_lds(
        (const __attribute__((address_space(1))) void*)g,
        (__attribute__((address_space(3))) void*)l, 16, 0, 0);
}

__global__ __launch_bounds__(256) void gemm_kernel(
    const i8* __restrict__ A, const i8* __restrict__ B,
    const bf16* __restrict__ Axo, const bf16* __restrict__ Bwc,
    const float* __restrict__ sx, const float* __restrict__ scale,
    const float* __restrict__ bias, float* __restrict__ C)
{
    constexpr int K = IC_K, N = OC_N, BK = 128, TM = 128, TN = 128;
    __shared__ __align__(16) i8 As[TM * BK];   // 16 KB
    __shared__ __align__(16) i8 Bs[TN * BK];   // 16 KB

    const int bm = blockIdx.y, bn = blockIdx.x;
    const int tid = threadIdx.x, lane = tid & 63, wave = tid >> 6;
    const int wm = wave >> 1, wn = wave & 1;

    // Staging: each inst covers 8 rows x 128 B. Lane l -> row l>>3, physical
    // 16B-quad l&7 which must hold logical quad (l&7)^(row&7).
    const int srow = lane >> 3;
    const int soct = (lane & 7) ^ srow;
    const i8* ga = A + (size_t)(bm * TM + wave * 32 + srow) * K + soct * 16;
    const i8* gb = B + (size_t)(bn * TN + wave * 32 + srow) * K + soct * 16;
    i8* lA = &As[wave * 32 * BK];
    i8* lB = &Bs[wave * 32 * BK];
    const int rxor = lane & 7;

    i32x4 acc[4][4] = {};

    for (int k0 = 0; k0 < K; k0 += BK) {
#pragma unroll
        for (int i = 0; i < 4; i++) {
            gload16(ga + k0 + (size_t)(i * 8) * K, lA + i * 8 * BK);
            gload16(gb + k0 + (size_t)(i * 8) * K, lB + i * 8 * BK);
        }
        __syncthreads();

#pragma unroll
        for (int s = 0; s < 2; s++) {
            const int lq = s * 4 + (lane >> 4);   // logical 16B-quad (k-group)
            const int pq = lq ^ rxor;
            i32x4 af[4], bfr[4];
#pragma unroll
            for (int i = 0; i < 4; i++)
                af[i] = *(const i32x4*)&As[(wm * 64 + i * 16 + (lane & 15)) * BK + pq * 16];
#pragma unroll
            for (int i = 0; i < 4; i++)
                bfr[i] = *(const i32x4*)&Bs[(wn * 64 + i * 16 + (lane & 15)) * BK + pq * 16];
#pragma unroll
            for (int mi = 0; mi < 4; mi++)
#pragma unroll
                for (int ni = 0; ni < 4; ni++)
                    acc[mi][ni] = __builtin_amdgcn_mfma_i32_16x16x64_i8(
                        af[mi], bfr[ni], acc[mi][ni], 0, 0, 0);
        }
        __syncthreads();
    }

    // ---- scale i32 -> f32: facc = acc * sx[row] * scale[col] ----
    // C/D layout: col = lane&15, row = (lane>>4)*4 + reg
    const int col0 = bn * TN + wn * 64 + (lane & 15);
    const int row0 = bm * TM + wm * 64 + (lane >> 4) * 4;
    float scl[4];
#pragma unroll
    for (int ni = 0; ni < 4; ni++) scl[ni] = scale[col0 + ni * 16];
    f32x4 facc[4][4];
#pragma unroll
    for (int mi = 0; mi < 4; mi++) {
        float sxv[4];
#pragma unroll
        for (int r = 0; r < 4; r++) sxv[r] = sx[row0 + mi * 16 + r];
#pragma unroll
        for (int ni = 0; ni < 4; ni++)
#pragma unroll
            for (int r = 0; r < 4; r++)
                facc[mi][ni][r] = (float)acc[mi][ni][r] * sxv[r] * scl[ni];
    }

    // ---- correction: 4 bf16 iterations over KC=256, BK2=64 (128B rows) ----
    bf16* As2 = (bf16*)As;
    bf16* Bs2 = (bf16*)Bs;
    const bf16* ga2 = Axo + (size_t)(bm * TM + wave * 32 + srow) * KC + soct * 8;
    const bf16* gb2 = Bwc + (size_t)(bn * TN + wave * 32 + srow) * KC + soct * 8;
    bf16* lA2 = As2 + wave * 32 * 64;
    bf16* lB2 = Bs2 + wave * 32 * 64;

    for (int k0 = 0; k0 < KC; k0 += 64) {
#pragma unroll
        for (int i = 0; i < 4; i++) {
            gload16(ga2 + k0 + (size_t)(i * 8) * KC, lA2 + i * 8 * 64);
            gload16(gb2 + k0 + (size_t)(i * 8) * KC, lB2 + i * 8 * 64);
        }
        __syncthreads();

#pragma unroll
        for (int s = 0; s < 2; s++) {
            const int lq = s * 4 + (lane >> 4);
            const int pq = lq ^ rxor;
            bf16x8 af2[4], bf2[4];
#pragma unroll
            for (int i = 0; i < 4; i++)
                af2[i] = *(const bf16x8*)&As2[(wave >> 1) * 0 + (wm * 64 + i * 16 + (lane & 15)) * 64 + pq * 8];
#pragma unroll
            for (int i = 0; i < 4; i++)
                bf2[i] = *(const bf16x8*)&Bs2[(wn * 64 + i * 16 + (lane & 15)) * 64 + pq * 8];
#pragma unroll
            for (int mi = 0; mi < 4; mi++)
#pragma unroll
                for (int ni = 0; ni < 4; ni++)
                    facc[mi][ni] = __builtin_amdgcn_mfma_f32_16x16x32_bf16(
                        af2[mi], bf2[ni], facc[mi][ni], 0, 0, 0);
        }
        __syncthreads();
    }

    // ---- epilogue: + bias, store ----
#pragma unroll
    for (int ni = 0; ni < 4; ni++) {
        const float bv = bias[col0 + ni * 16];
#pragma unroll
        for (int mi = 0; mi < 4; mi++) {
#pragma unroll
            for (int r = 0; r < 4; r++) {
                C[(size_t)(row0 + mi * 16 + r) * N + col0 + ni * 16] =
                    facc[mi][ni][r] + bv;
            }
        }
    }
}

// ---------------------------------------------------------------------------
extern "C" void kernel_launch(void* const* d_in, const int* in_sizes, int n_in,
                              void* d_out, int out_size, void* d_ws, size_t ws_size,
                              hipStream_t stream)
{
    const float* x    = (const float*)d_in[0];
    const float* w    = (const float*)d_in[1];
    const float* bias = (const float*)d_in[2];
    const float* ow   = (const float*)d_in[3];
    const int*   idx  = (const int*)d_in[4];
    const int    n_out = in_sizes[4];
    float* out = (float*)d_out;

    char* ws = (char*)d_ws;
    i8*    xq    = (i8*)ws;                                   // 16 MB
    i8*    wsgn  = (i8*)(ws + (size_t)16 * 1024 * 1024);      // 16 MB
    bf16*  xo    = (bf16*)(ws + (size_t)32 * 1024 * 1024);    // 2 MB
    bf16*  wcorr = (bf16*)(ws + (size_t)34 * 1024 * 1024);    // 2 MB
    float* sx    = (float*)(ws + (size_t)36 * 1024 * 1024);   // 16 KB
    float* scl   = (float*)(ws + (size_t)36 * 1024 * 1024 + 16 * 1024); // 16 KB

    hipLaunchKernelGGL(prep_kernel, dim3(OC_N), dim3(256), 0, stream,
                       w, x, ow, idx, wsgn, xq, xo, wcorr, scl, sx, n_out);
    hipLaunchKernelGGL(gemm_kernel, dim3(OC_N / 128, TOKENS / 128), dim3(256),
                       0, stream, xq, wsgn, xo, wcorr, sx, scl, bias, out);
}

// Round 5
// 256.301 us; speedup vs baseline: 1.3744x; 1.0077x over previous
//
#include <hip/hip_runtime.h>

typedef __bf16 bf16;
typedef __bf16 bf16x8 __attribute__((ext_vector_type(8)));
typedef float  f32x4  __attribute__((ext_vector_type(4)));
typedef float  f32x16 __attribute__((ext_vector_type(16)));
typedef int    i32x4  __attribute__((ext_vector_type(4)));
typedef int    i32x16 __attribute__((ext_vector_type(16)));
typedef signed char i8;

#define OC_N   4096
#define IC_K   4096
#define TOKENS 4096
#define KC     256   // outlier K padded to 8x32

// ---------------------------------------------------------------------------
// Fused prep, one block per row r (TOKENS == OC_N == 4096):
//   A: weight row -> mean, scale=mean|w-mean|, sign i8 {-1,0,1}; scale_arr
//   B: x row -> per-token absmax, sx=max/127, x i8; sx_arr
//   C: correction arrays (KC=256 padded):
//        xo[r][c]    = bf16( x[r][idx[c]] )
//        wcorr[r][c] = bf16( ow[r][c] - scale*sign(w[r][idx[c]]-mean) )
// ---------------------------------------------------------------------------
__global__ __launch_bounds__(256) void prep_kernel(
    const float* __restrict__ w, const float* __restrict__ x,
    const float* __restrict__ ow, const int* __restrict__ idx,
    i8* __restrict__ wsgn, i8* __restrict__ xq,
    bf16* __restrict__ xo, bf16* __restrict__ wcorr,
    float* __restrict__ scale_arr, float* __restrict__ sx_arr, int n_out)
{
    __shared__ float red[8];
    const int row = blockIdx.x;
    const int t = threadIdx.x;
    const int lane = t & 63, wv = t >> 6;

    // ---- phase A: weight row ----
    const float4* wr = (const float4*)(w + (size_t)row * IC_K);
    float4 v[4];
    float s = 0.f;
#pragma unroll
    for (int i = 0; i < 4; i++) {
        v[i] = wr[i * 256 + t];
        s += v[i].x + v[i].y + v[i].z + v[i].w;
    }
    for (int o = 32; o > 0; o >>= 1) s += __shfl_down(s, o, 64);
    if (lane == 0) red[wv] = s;
    __syncthreads();
    const float mean = (red[0] + red[1] + red[2] + red[3]) * (1.f / IC_K);

    float sa = 0.f;
#pragma unroll
    for (int i = 0; i < 4; i++) {
        sa += fabsf(v[i].x - mean) + fabsf(v[i].y - mean) +
              fabsf(v[i].z - mean) + fabsf(v[i].w - mean);
    }
    for (int o = 32; o > 0; o >>= 1) sa += __shfl_down(sa, o, 64);
    if (lane == 0) red[4 + wv] = sa;
    __syncthreads();
    const float scale = (red[4] + red[5] + red[6] + red[7]) * (1.f / IC_K);

    i8* srow = wsgn + (size_t)row * IC_K;
#pragma unroll
    for (int i = 0; i < 4; i++) {
        float c[4] = { v[i].x - mean, v[i].y - mean, v[i].z - mean, v[i].w - mean };
        char4 q;
        q.x = (i8)((c[0] > 0.f) - (c[0] < 0.f));
        q.y = (i8)((c[1] > 0.f) - (c[1] < 0.f));
        q.z = (i8)((c[2] > 0.f) - (c[2] < 0.f));
        q.w = (i8)((c[3] > 0.f) - (c[3] < 0.f));
        *(char4*)(srow + (size_t)(i * 256 + t) * 4) = q;
    }

    // ---- phase B: x row quantization ----
    const float4* xr = (const float4*)(x + (size_t)row * IC_K);
    float4 u[4];
    float mx = 0.f;
#pragma unroll
    for (int i = 0; i < 4; i++) {
        u[i] = xr[i * 256 + t];
        mx = fmaxf(mx, fmaxf(fmaxf(fabsf(u[i].x), fabsf(u[i].y)),
                             fmaxf(fabsf(u[i].z), fabsf(u[i].w))));
    }
    for (int o = 32; o > 0; o >>= 1) mx = fmaxf(mx, __shfl_down(mx, o, 64));
    if (lane == 0) red[wv] = mx;
    __syncthreads();
    const float maxv = fmaxf(fmaxf(red[0], red[1]), fmaxf(red[2], red[3]));
    const float inv = maxv > 0.f ? 127.f / maxv : 0.f;
    const float sxv = maxv > 0.f ? maxv * (1.f / 127.f) : 1.f;

    i8* xrow = xq + (size_t)row * IC_K;
#pragma unroll
    for (int i = 0; i < 4; i++) {
        char4 q;
        q.x = (i8)(int)rintf(u[i].x * inv);
        q.y = (i8)(int)rintf(u[i].y * inv);
        q.z = (i8)(int)rintf(u[i].z * inv);
        q.w = (i8)(int)rintf(u[i].w * inv);
        *(char4*)(xrow + (size_t)(i * 256 + t) * 4) = q;
    }
    if (t == 0) { scale_arr[row] = scale; sx_arr[row] = sxv; }

    // ---- phase C: correction arrays ----
    if (t < n_out) {
        const int col = idx[t];
        xo[(size_t)row * KC + t] = (bf16)x[(size_t)row * IC_K + col];
        const float wc_ = w[(size_t)row * IC_K + col] - mean;
        const float sg = (wc_ > 0.f) ? 1.f : ((wc_ < 0.f) ? -1.f : 0.f);
        wcorr[(size_t)row * KC + t] = (bf16)(ow[(size_t)row * n_out + t] - scale * sg);
    } else if (t < KC) {
        xo[(size_t)row * KC + t] = (bf16)0.f;
        wcorr[(size_t)row * KC + t] = (bf16)0.f;
    }
}

// ---------------------------------------------------------------------------
// GEMM: C = sx[t]*scale[o]*(xq @ wsgn^T)_i32 + xo @ wcorr^T + bias
// 128x128 tile, rows of 128 B in LDS, generalized XOR swizzle
//   f(row) = (row ^ (row>>3)) & 7   (16B-quad q of row lives at q ^ f(row))
// applied on the global-fetch side of global_load_lds. Main loop:
// mfma_i32_32x32x32_i8, 2x2 tiles of 32x32 per wave (64x64 region).
// Correction loop: 4 iterations of bf16 K=64 with mfma_f32_32x32x16_bf16
// accumulating into the scaled f32 accumulators (same C/D layout).
// K-quad permutation is identical for A and B so it cancels in the MFMA.
// ---------------------------------------------------------------------------
__device__ __forceinline__ void gload16(const void* g, void* l)
{
    __builtin_amdgcn_global_load_lds(
        (const __attribute__((address_space(1))) void*)g,
        (__attribute__((address_space(3))) void*)l, 16, 0, 0);
}

__global__ __launch_bounds__(256) void gemm_kernel(
    const i8* __restrict__ A, const i8* __restrict__ B,
    const bf16* __restrict__ Axo, const bf16* __restrict__ Bwc,
    const float* __restrict__ sx, const float* __restrict__ scale,
    const float* __restrict__ bias, float* __restrict__ C)
{
    constexpr int K = IC_K, N = OC_N, BK = 128, TM = 128, TN = 128;
    __shared__ __align__(16) i8 As[TM * BK];   // 16 KB
    __shared__ __align__(16) i8 Bs[TN * BK];   // 16 KB

    const int bm = blockIdx.y, bn = blockIdx.x;
    const int tid = threadIdx.x, lane = tid & 63, wave = tid >> 6;
    const int wm = wave >> 1, wn = wave & 1;

    // Staging: inst i covers 8 rows x 128 B (chunk c = wave*4+i). Lane l ->
    // row l>>3, phys quad l&7, which must hold logical quad (l&7)^f(row),
    // f(row) = (row&7) ^ ((row>>3)&7) = srow ^ ((wave*4+i)&7).
    const int srow = lane >> 3;
    const int q0 = (lane & 7) ^ srow ^ ((wave & 1) * 4); // logical quad for i=0
    const i8* ga = A + (size_t)(bm * TM + wave * 32 + srow) * K;
    const i8* gb = B + (size_t)(bn * TN + wave * 32 + srow) * K;
    i8* lA = &As[wave * 32 * BK];
    i8* lB = &Bs[wave * 32 * BK];

    // Fragment-read indices (32x32 shapes): m/n = lane&31, k-group = lane>>5.
    const int kg = lane >> 5;
    const int m32 = lane & 31;
    const int frb = (lane & 7) ^ ((lane >> 3) & 3);  // f(row) sans ti-term

    i32x16 acc[2][2] = {};

    for (int k0 = 0; k0 < K; k0 += BK) {
#pragma unroll
        for (int i = 0; i < 4; i++) {
            gload16(ga + k0 + (size_t)(i * 8) * K + (q0 ^ i) * 16, lA + i * 8 * BK);
            gload16(gb + k0 + (size_t)(i * 8) * K + (q0 ^ i) * 16, lB + i * 8 * BK);
        }
        __syncthreads();

#pragma unroll
        for (int t = 0; t < 4; t++) {
            i32x4 af[2], bfr[2];
#pragma unroll
            for (int ti = 0; ti < 2; ti++) {
                const int pq = ((t << 1) | kg) ^ frb ^ (ti << 2);
                af[ti]  = *(const i32x4*)&As[(wm * 64 + ti * 32 + m32) * BK + pq * 16];
                bfr[ti] = *(const i32x4*)&Bs[(wn * 64 + ti * 32 + m32) * BK + pq * 16];
            }
#pragma unroll
            for (int mi = 0; mi < 2; mi++)
#pragma unroll
                for (int ni = 0; ni < 2; ni++)
                    acc[mi][ni] = __builtin_amdgcn_mfma_i32_32x32x32_i8(
                        af[mi], bfr[ni], acc[mi][ni], 0, 0, 0);
        }
        __syncthreads();
    }

    // ---- scale i32 -> f32 ----
    // 32x32 C/D layout: col = lane&31, row = (reg&3) + 8*(reg>>2) + 4*(lane>>5)
    const int col0 = bn * TN + wn * 64 + m32;
    const int rbase = bm * TM + wm * 64 + 4 * kg;
    float scl2[2], bv[2];
#pragma unroll
    for (int ni = 0; ni < 2; ni++) {
        scl2[ni] = scale[col0 + ni * 32];
        bv[ni]   = bias[col0 + ni * 32];
    }
    f32x16 facc[2][2];
#pragma unroll
    for (int mi = 0; mi < 2; mi++) {
#pragma unroll
        for (int reg = 0; reg < 16; reg++) {
            const float sxv = sx[rbase + mi * 32 + (reg & 3) + 8 * (reg >> 2)];
#pragma unroll
            for (int ni = 0; ni < 2; ni++)
                facc[mi][ni][reg] = (float)acc[mi][ni][reg] * sxv * scl2[ni];
        }
    }

    // ---- correction: 4 bf16 iterations over KC=256 (rows of 64 bf16 = 128 B) ----
    bf16* As2 = (bf16*)As;
    bf16* Bs2 = (bf16*)Bs;
    const bf16* ga2 = Axo + (size_t)(bm * TM + wave * 32 + srow) * KC;
    const bf16* gb2 = Bwc + (size_t)(bn * TN + wave * 32 + srow) * KC;
    bf16* lA2 = As2 + wave * 32 * 64;
    bf16* lB2 = Bs2 + wave * 32 * 64;

    for (int k0 = 0; k0 < KC; k0 += 64) {
#pragma unroll
        for (int i = 0; i < 4; i++) {
            gload16(ga2 + k0 + (size_t)(i * 8) * KC + (q0 ^ i) * 8, lA2 + i * 8 * 64);
            gload16(gb2 + k0 + (size_t)(i * 8) * KC + (q0 ^ i) * 8, lB2 + i * 8 * 64);
        }
        __syncthreads();

#pragma unroll
        for (int t = 0; t < 4; t++) {
            bf16x8 af2[2], bf2[2];
#pragma unroll
            for (int ti = 0; ti < 2; ti++) {
                const int pq = ((t << 1) | kg) ^ frb ^ (ti << 2);
                af2[ti] = *(const bf16x8*)&As2[(wm * 64 + ti * 32 + m32) * 64 + pq * 8];
                bf2[ti] = *(const bf16x8*)&Bs2[(wn * 64 + ti * 32 + m32) * 64 + pq * 8];
            }
#pragma unroll
            for (int mi = 0; mi < 2; mi++)
#pragma unroll
                for (int ni = 0; ni < 2; ni++)
                    facc[mi][ni] = __builtin_amdgcn_mfma_f32_32x32x16_bf16(
                        af2[mi], bf2[ni], facc[mi][ni], 0, 0, 0);
        }
        __syncthreads();
    }

    // ---- epilogue: + bias, store ----
#pragma unroll
    for (int mi = 0; mi < 2; mi++) {
#pragma unroll
        for (int reg = 0; reg < 16; reg++) {
            const int row = rbase + mi * 32 + (reg & 3) + 8 * (reg >> 2);
#pragma unroll
            for (int ni = 0; ni < 2; ni++)
                C[(size_t)row * N + col0 + ni * 32] = facc[mi][ni][reg] + bv[ni];
        }
    }
}

// ---------------------------------------------------------------------------
extern "C" void kernel_launch(void* const* d_in, const int* in_sizes, int n_in,
                              void* d_out, int out_size, void* d_ws, size_t ws_size,
                              hipStream_t stream)
{
    const float* x    = (const float*)d_in[0];
    const float* w    = (const float*)d_in[1];
    const float* bias = (const float*)d_in[2];
    const float* ow   = (const float*)d_in[3];
    const int*   idx  = (const int*)d_in[4];
    const int    n_out = in_sizes[4];
    float* out = (float*)d_out;

    char* ws = (char*)d_ws;
    i8*    xq    = (i8*)ws;                                   // 16 MB
    i8*    wsgn  = (i8*)(ws + (size_t)16 * 1024 * 1024);      // 16 MB
    bf16*  xo    = (bf16*)(ws + (size_t)32 * 1024 * 1024);    // 2 MB
    bf16*  wcorr = (bf16*)(ws + (size_t)34 * 1024 * 1024);    // 2 MB
    float* sx    = (float*)(ws + (size_t)36 * 1024 * 1024);   // 16 KB
    float* scl   = (float*)(ws + (size_t)36 * 1024 * 1024 + 16 * 1024); // 16 KB

    hipLaunchKernelGGL(prep_kernel, dim3(OC_N), dim3(256), 0, stream,
                       w, x, ow, idx, wsgn, xq, xo, wcorr, scl, sx, n_out);
    hipLaunchKernelGGL(gemm_kernel, dim3(OC_N / 128, TOKENS / 128), dim3(256),
                       0, stream, xq, wsgn, xo, wcorr, sx, scl, bias, out);
}

// Round 6
// 253.036 us; speedup vs baseline: 1.3922x; 1.0129x over previous
//
#include <hip/hip_runtime.h>

typedef __bf16 bf16;
typedef __bf16 bf16x8 __attribute__((ext_vector_type(8)));
typedef float  f32x4  __attribute__((ext_vector_type(4)));
typedef float  f32x16 __attribute__((ext_vector_type(16)));
typedef int    i32x4  __attribute__((ext_vector_type(4)));
typedef int    i32x16 __attribute__((ext_vector_type(16)));
typedef signed char i8;

#define OC_N   4096
#define IC_K   4096
#define TOKENS 4096
#define KC     256   // outlier K padded to 8x32

// ---------------------------------------------------------------------------
// Fused prep, one block per row r (TOKENS == OC_N == 4096).
// ALL global loads issued at kernel entry (w row, x row, phase-C gathers) so
// a single latency drain covers them; reductions/stores follow.
//   A: weight row -> mean, scale=mean|w-mean|, sign i8 {-1,0,1}; scale_arr
//   B: x row -> per-token absmax, sx=max/127, x i8; sx_arr
//   C: correction arrays (KC=256 padded):
//        xo[r][c]    = bf16( x[r][idx[c]] )
//        wcorr[r][c] = bf16( ow[r][c] - scale*sign(w[r][idx[c]]-mean) )
// ---------------------------------------------------------------------------
__global__ __launch_bounds__(256) void prep_kernel(
    const float* __restrict__ w, const float* __restrict__ x,
    const float* __restrict__ ow, const int* __restrict__ idx,
    i8* __restrict__ wsgn, i8* __restrict__ xq,
    bf16* __restrict__ xo, bf16* __restrict__ wcorr,
    float* __restrict__ scale_arr, float* __restrict__ sx_arr, int n_out)
{
    __shared__ float red[8];
    const int row = blockIdx.x;
    const int t = threadIdx.x;
    const int lane = t & 63, wv = t >> 6;

    // ---- issue every global load up front ----
    const float4* wr = (const float4*)(w + (size_t)row * IC_K);
    const float4* xr = (const float4*)(x + (size_t)row * IC_K);
    float4 v[4], u[4];
#pragma unroll
    for (int i = 0; i < 4; i++) v[i] = wr[i * 256 + t];
#pragma unroll
    for (int i = 0; i < 4; i++) u[i] = xr[i * 256 + t];

    float xg = 0.f, wg = 0.f, og = 0.f;
    if (t < n_out) {
        const int colg = idx[t];
        xg = x[(size_t)row * IC_K + colg];
        wg = w[(size_t)row * IC_K + colg];
        og = ow[(size_t)row * n_out + t];
    }

    // ---- phase A: weight row mean ----
    float s = 0.f;
#pragma unroll
    for (int i = 0; i < 4; i++)
        s += v[i].x + v[i].y + v[i].z + v[i].w;
    for (int o = 32; o > 0; o >>= 1) s += __shfl_down(s, o, 64);
    if (lane == 0) red[wv] = s;
    __syncthreads();
    const float mean = (red[0] + red[1] + red[2] + red[3]) * (1.f / IC_K);

    float sa = 0.f;
#pragma unroll
    for (int i = 0; i < 4; i++) {
        sa += fabsf(v[i].x - mean) + fabsf(v[i].y - mean) +
              fabsf(v[i].z - mean) + fabsf(v[i].w - mean);
    }
    for (int o = 32; o > 0; o >>= 1) sa += __shfl_down(sa, o, 64);
    if (lane == 0) red[4 + wv] = sa;
    __syncthreads();
    const float scale = (red[4] + red[5] + red[6] + red[7]) * (1.f / IC_K);

    i8* srow = wsgn + (size_t)row * IC_K;
#pragma unroll
    for (int i = 0; i < 4; i++) {
        float c[4] = { v[i].x - mean, v[i].y - mean, v[i].z - mean, v[i].w - mean };
        char4 q;
        q.x = (i8)((c[0] > 0.f) - (c[0] < 0.f));
        q.y = (i8)((c[1] > 0.f) - (c[1] < 0.f));
        q.z = (i8)((c[2] > 0.f) - (c[2] < 0.f));
        q.w = (i8)((c[3] > 0.f) - (c[3] < 0.f));
        *(char4*)(srow + (size_t)(i * 256 + t) * 4) = q;
    }

    // ---- phase B: x row quantization (loads already in flight) ----
    float mx = 0.f;
#pragma unroll
    for (int i = 0; i < 4; i++)
        mx = fmaxf(mx, fmaxf(fmaxf(fabsf(u[i].x), fabsf(u[i].y)),
                             fmaxf(fabsf(u[i].z), fabsf(u[i].w))));
    for (int o = 32; o > 0; o >>= 1) mx = fmaxf(mx, __shfl_down(mx, o, 64));
    if (lane == 0) red[wv] = mx;   // red[0..3] readers (mean) all done pre-sync2
    __syncthreads();
    const float maxv = fmaxf(fmaxf(red[0], red[1]), fmaxf(red[2], red[3]));
    const float inv = maxv > 0.f ? 127.f / maxv : 0.f;
    const float sxv = maxv > 0.f ? maxv * (1.f / 127.f) : 1.f;

    i8* xrow = xq + (size_t)row * IC_K;
#pragma unroll
    for (int i = 0; i < 4; i++) {
        char4 q;
        q.x = (i8)(int)rintf(u[i].x * inv);
        q.y = (i8)(int)rintf(u[i].y * inv);
        q.z = (i8)(int)rintf(u[i].z * inv);
        q.w = (i8)(int)rintf(u[i].w * inv);
        *(char4*)(xrow + (size_t)(i * 256 + t) * 4) = q;
    }
    if (t == 0) { scale_arr[row] = scale; sx_arr[row] = sxv; }

    // ---- phase C: correction arrays (gathers loaded at entry) ----
    if (t < n_out) {
        xo[(size_t)row * KC + t] = (bf16)xg;
        const float wc_ = wg - mean;
        const float sg = (wc_ > 0.f) ? 1.f : ((wc_ < 0.f) ? -1.f : 0.f);
        wcorr[(size_t)row * KC + t] = (bf16)(og - scale * sg);
    } else if (t < KC) {
        xo[(size_t)row * KC + t] = (bf16)0.f;
        wcorr[(size_t)row * KC + t] = (bf16)0.f;
    }
}

// ---------------------------------------------------------------------------
// GEMM: C = sx[t]*scale[o]*(xq @ wsgn^T)_i32 + xo @ wcorr^T + bias
// 128x128 tile, rows of 128 B in LDS, generalized XOR swizzle
//   f(row) = (row ^ (row>>3)) & 7   (16B-quad q of row lives at q ^ f(row))
// applied on the global-fetch side of global_load_lds. Main loop:
// mfma_i32_32x32x32_i8, 2x2 tiles of 32x32 per wave (64x64 region).
// Correction loop: 4 iterations of bf16 K=64 with mfma_f32_32x32x16_bf16.
// K-quad permutation is identical for A and B so it cancels in the MFMA.
// [R5 verified: SQ_LDS_BANK_CONFLICT == 0, absmax 0.0547 — UNCHANGED THIS ROUND]
// ---------------------------------------------------------------------------
__device__ __forceinline__ void gload16(const void* g, void* l)
{
    __builtin_amdgcn_global_load_lds(
        (const __attribute__((address_space(1))) void*)g,
        (__attribute__((address_space(3))) void*)l, 16, 0, 0);
}

__global__ __launch_bounds__(256) void gemm_kernel(
    const i8* __restrict__ A, const i8* __restrict__ B,
    const bf16* __restrict__ Axo, const bf16* __restrict__ Bwc,
    const float* __restrict__ sx, const float* __restrict__ scale,
    const float* __restrict__ bias, float* __restrict__ C)
{
    constexpr int K = IC_K, N = OC_N, BK = 128, TM = 128, TN = 128;
    __shared__ __align__(16) i8 As[TM * BK];   // 16 KB
    __shared__ __align__(16) i8 Bs[TN * BK];   // 16 KB

    const int bm = blockIdx.y, bn = blockIdx.x;
    const int tid = threadIdx.x, lane = tid & 63, wave = tid >> 6;
    const int wm = wave >> 1, wn = wave & 1;

    const int srow = lane >> 3;
    const int q0 = (lane & 7) ^ srow ^ ((wave & 1) * 4); // logical quad for i=0
    const i8* ga = A + (size_t)(bm * TM + wave * 32 + srow) * K;
    const i8* gb = B + (size_t)(bn * TN + wave * 32 + srow) * K;
    i8* lA = &As[wave * 32 * BK];
    i8* lB = &Bs[wave * 32 * BK];

    const int kg = lane >> 5;
    const int m32 = lane & 31;
    const int frb = (lane & 7) ^ ((lane >> 3) & 3);

    i32x16 acc[2][2] = {};

    for (int k0 = 0; k0 < K; k0 += BK) {
#pragma unroll
        for (int i = 0; i < 4; i++) {
            gload16(ga + k0 + (size_t)(i * 8) * K + (q0 ^ i) * 16, lA + i * 8 * BK);
            gload16(gb + k0 + (size_t)(i * 8) * K + (q0 ^ i) * 16, lB + i * 8 * BK);
        }
        __syncthreads();

#pragma unroll
        for (int t = 0; t < 4; t++) {
            i32x4 af[2], bfr[2];
#pragma unroll
            for (int ti = 0; ti < 2; ti++) {
                const int pq = ((t << 1) | kg) ^ frb ^ (ti << 2);
                af[ti]  = *(const i32x4*)&As[(wm * 64 + ti * 32 + m32) * BK + pq * 16];
                bfr[ti] = *(const i32x4*)&Bs[(wn * 64 + ti * 32 + m32) * BK + pq * 16];
            }
#pragma unroll
            for (int mi = 0; mi < 2; mi++)
#pragma unroll
                for (int ni = 0; ni < 2; ni++)
                    acc[mi][ni] = __builtin_amdgcn_mfma_i32_32x32x32_i8(
                        af[mi], bfr[ni], acc[mi][ni], 0, 0, 0);
        }
        __syncthreads();
    }

    // ---- scale i32 -> f32 ----
    // 32x32 C/D layout: col = lane&31, row = (reg&3) + 8*(reg>>2) + 4*(lane>>5)
    const int col0 = bn * TN + wn * 64 + m32;
    const int rbase = bm * TM + wm * 64 + 4 * kg;
    float scl2[2], bv[2];
#pragma unroll
    for (int ni = 0; ni < 2; ni++) {
        scl2[ni] = scale[col0 + ni * 32];
        bv[ni]   = bias[col0 + ni * 32];
    }
    f32x16 facc[2][2];
#pragma unroll
    for (int mi = 0; mi < 2; mi++) {
#pragma unroll
        for (int reg = 0; reg < 16; reg++) {
            const float sxv = sx[rbase + mi * 32 + (reg & 3) + 8 * (reg >> 2)];
#pragma unroll
            for (int ni = 0; ni < 2; ni++)
                facc[mi][ni][reg] = (float)acc[mi][ni][reg] * sxv * scl2[ni];
        }
    }

    // ---- correction: 4 bf16 iterations over KC=256 (rows of 64 bf16 = 128 B) ----
    bf16* As2 = (bf16*)As;
    bf16* Bs2 = (bf16*)Bs;
    const bf16* ga2 = Axo + (size_t)(bm * TM + wave * 32 + srow) * KC;
    const bf16* gb2 = Bwc + (size_t)(bn * TN + wave * 32 + srow) * KC;
    bf16* lA2 = As2 + wave * 32 * 64;
    bf16* lB2 = Bs2 + wave * 32 * 64;

    for (int k0 = 0; k0 < KC; k0 += 64) {
#pragma unroll
        for (int i = 0; i < 4; i++) {
            gload16(ga2 + k0 + (size_t)(i * 8) * KC + (q0 ^ i) * 8, lA2 + i * 8 * 64);
            gload16(gb2 + k0 + (size_t)(i * 8) * KC + (q0 ^ i) * 8, lB2 + i * 8 * 64);
        }
        __syncthreads();

#pragma unroll
        for (int t = 0; t < 4; t++) {
            bf16x8 af2[2], bf2[2];
#pragma unroll
            for (int ti = 0; ti < 2; ti++) {
                const int pq = ((t << 1) | kg) ^ frb ^ (ti << 2);
                af2[ti] = *(const bf16x8*)&As2[(wm * 64 + ti * 32 + m32) * 64 + pq * 8];
                bf2[ti] = *(const bf16x8*)&Bs2[(wn * 64 + ti * 32 + m32) * 64 + pq * 8];
            }
#pragma unroll
            for (int mi = 0; mi < 2; mi++)
#pragma unroll
                for (int ni = 0; ni < 2; ni++)
                    facc[mi][ni] = __builtin_amdgcn_mfma_f32_32x32x16_bf16(
                        af2[mi], bf2[ni], facc[mi][ni], 0, 0, 0);
        }
        __syncthreads();
    }

    // ---- epilogue: + bias, store ----
#pragma unroll
    for (int mi = 0; mi < 2; mi++) {
#pragma unroll
        for (int reg = 0; reg < 16; reg++) {
            const int row = rbase + mi * 32 + (reg & 3) + 8 * (reg >> 2);
#pragma unroll
            for (int ni = 0; ni < 2; ni++)
                C[(size_t)row * N + col0 + ni * 32] = facc[mi][ni][reg] + bv[ni];
        }
    }
}

// ---------------------------------------------------------------------------
extern "C" void kernel_launch(void* const* d_in, const int* in_sizes, int n_in,
                              void* d_out, int out_size, void* d_ws, size_t ws_size,
                              hipStream_t stream)
{
    const float* x    = (const float*)d_in[0];
    const float* w    = (const float*)d_in[1];
    const float* bias = (const float*)d_in[2];
    const float* ow   = (const float*)d_in[3];
    const int*   idx  = (const int*)d_in[4];
    const int    n_out = in_sizes[4];
    float* out = (float*)d_out;

    char* ws = (char*)d_ws;
    i8*    xq    = (i8*)ws;                                   // 16 MB
    i8*    wsgn  = (i8*)(ws + (size_t)16 * 1024 * 1024);      // 16 MB
    bf16*  xo    = (bf16*)(ws + (size_t)32 * 1024 * 1024);    // 2 MB
    bf16*  wcorr = (bf16*)(ws + (size_t)34 * 1024 * 1024);    // 2 MB
    float* sx    = (float*)(ws + (size_t)36 * 1024 * 1024);   // 16 KB
    float* scl   = (float*)(ws + (size_t)36 * 1024 * 1024 + 16 * 1024); // 16 KB

    hipLaunchKernelGGL(prep_kernel, dim3(OC_N), dim3(256), 0, stream,
                       w, x, ow, idx, wsgn, xq, xo, wcorr, scl, sx, n_out);
    hipLaunchKernelGGL(gemm_kernel, dim3(OC_N / 128, TOKENS / 128), dim3(256),
                       0, stream, xq, wsgn, xo, wcorr, sx, scl, bias, out);
}